// Round 1
// baseline (199.863 us; speedup 1.0000x reference)
//
#include <hip/hip_runtime.h>
#include <math.h>

#define NQ 12
#define DIM 4096          // 2^12 amplitudes
#define NLAYERS 3

// CNOT ring i->(i+1)%12 composes to a linear bit permutation F.
// new_state[c] = old_state[F^{-1}(c)], with
// F^{-1}(c) = ((c ^ (c<<1)) & 0xFFF) ^ (bit11(c) ? 3 : 0)
__device__ __forceinline__ int cnot_inv(int c) {
    int b = (c ^ (c << 1)) & 0xFFF;
    b ^= (c >> 11) * 3;
    return b;
}

__global__ __launch_bounds__(256, 4)
void qreup_kernel(const float* __restrict__ x,
                  const float* __restrict__ rw,   // [12,3,4]
                  const float* __restrict__ rb,   // [12,3]
                  const float* __restrict__ w1,   // [64,12]
                  const float* __restrict__ b1,   // [64]
                  const float* __restrict__ w2,   // [256,64]
                  const float* __restrict__ b2,   // [256]
                  float* __restrict__ out)        // [B,256]
{
    __shared__ float2 st[DIM];       // 32 KB statevector
    __shared__ float  u[NQ][8];      // 12 U3 matrices (complex 2x2)
    __shared__ float  zred[4][12];
    __shared__ float  qzs[12];
    __shared__ float  hbuf[64];

    const int t = threadIdx.x;
    const int b = blockIdx.x;

    // ---- Phase A: per-chunk affine params -> U3 matrices (threads 0..11)
    if (t < NQ) {
        const int c = t;
        const float4 xv = ((const float4*)x)[b * 12 + c];   // x[b, 4c..4c+3]
        float prm[3];
        #pragma unroll
        for (int p = 0; p < 3; ++p) {
            const float4 wv = ((const float4*)rw)[c * 3 + p];
            prm[p] = rb[c * 3 + p] + wv.x * xv.x + wv.y * xv.y + wv.z * xv.z + wv.w * xv.w;
        }
        float st_, ct_; sincosf(0.5f * prm[0], &st_, &ct_);
        float sp, cp;   sincosf(prm[1], &sp, &cp);
        float sl, cl;   sincosf(prm[2], &sl, &cl);
        const float cpl = cp * cl - sp * sl;
        const float spl = sp * cl + cp * sl;
        // U3 = [[ct, -e^{il} st], [e^{ip} st, e^{i(p+l)} ct]]
        u[c][0] = ct_;        u[c][1] = 0.0f;
        u[c][2] = -cl * st_;  u[c][3] = -sl * st_;
        u[c][4] = cp * st_;   u[c][5] = sp * st_;
        u[c][6] = cpl * ct_;  u[c][7] = spl * ct_;
    }

    // ---- init |0...0>
    #pragma unroll
    for (int r = 0; r < 16; ++r) {
        const int i = t + (r << 8);
        st[i] = make_float2(i == 0 ? 1.0f : 0.0f, 0.0f);
    }

    // ---- 3 layers x (12 U3 gates + CNOT-ring permutation)
    for (int layer = 0; layer < NLAYERS; ++layer) {
        for (int w = 0; w < NQ; ++w) {
            __syncthreads();
            const float u00r = u[w][0], u00i = u[w][1];
            const float u01r = u[w][2], u01i = u[w][3];
            const float u10r = u[w][4], u10i = u[w][5];
            const float u11r = u[w][6], u11i = u[w][7];
            const int bitw = 1 << w;
            const int mask = bitw - 1;

            float2 a0[8], a1[8];
            int    i0s[8];
            #pragma unroll
            for (int r = 0; r < 8; ++r) {
                const int p  = t + (r << 8);            // pair id, lane-contiguous
                const int i0 = ((p & ~mask) << 1) | (p & mask);
                i0s[r] = i0;
                a0[r] = st[i0];
                a1[r] = st[i0 | bitw];
            }
            #pragma unroll
            for (int r = 0; r < 8; ++r) {
                float2 n0, n1;
                n0.x = u00r*a0[r].x - u00i*a0[r].y + u01r*a1[r].x - u01i*a1[r].y;
                n0.y = u00r*a0[r].y + u00i*a0[r].x + u01r*a1[r].y + u01i*a1[r].x;
                n1.x = u10r*a0[r].x - u10i*a0[r].y + u11r*a1[r].x - u11i*a1[r].y;
                n1.y = u10r*a0[r].y + u10i*a0[r].x + u11r*a1[r].y + u11i*a1[r].x;
                st[i0s[r]]        = n0;
                st[i0s[r] | bitw] = n1;
            }
        }
        // CNOT ring as a single gather: new[c] = old[F^{-1}(c)]
        __syncthreads();
        float2 tmp[16];
        #pragma unroll
        for (int r = 0; r < 16; ++r) {
            const int c = t + (r << 8);
            tmp[r] = st[cnot_inv(c)];
        }
        __syncthreads();
        #pragma unroll
        for (int r = 0; r < 16; ++r) {
            st[t + (r << 8)] = tmp[r];
        }
    }

    // ---- measurement: z_i = sum_b |amp|^2 * (1 - 2*bit_i(b))
    __syncthreads();
    float ztot = 0.f, z8 = 0.f, z9 = 0.f, z10 = 0.f, z11 = 0.f;
    #pragma unroll
    for (int r = 0; r < 16; ++r) {
        const int c = t + (r << 8);   // bits 0..7 = t, bits 8..11 = r
        const float2 a = st[c];
        const float pr = a.x * a.x + a.y * a.y;
        ztot += pr;
        z8  += (r & 1) ? -pr : pr;
        z9  += (r & 2) ? -pr : pr;
        z10 += (r & 4) ? -pr : pr;
        z11 += (r & 8) ? -pr : pr;
    }
    float zp[12];
    #pragma unroll
    for (int i = 0; i < 8; ++i)
        zp[i] = ((t >> i) & 1) ? -ztot : ztot;
    zp[8] = z8; zp[9] = z9; zp[10] = z10; zp[11] = z11;

    #pragma unroll
    for (int i = 0; i < 12; ++i) {
        float v = zp[i];
        #pragma unroll
        for (int off = 32; off > 0; off >>= 1)
            v += __shfl_xor(v, off, 64);
        zp[i] = v;
    }
    const int wave = t >> 6;
    if ((t & 63) == 0) {
        #pragma unroll
        for (int i = 0; i < 12; ++i) zred[wave][i] = zp[i];
    }
    __syncthreads();
    if (t < 12)
        qzs[t] = zred[0][t] + zred[1][t] + zred[2][t] + zred[3][t];
    __syncthreads();

    // ---- MLP head: h = relu(qz @ w1.T + b1); out = h @ w2.T + b2
    if (t < 64) {
        float acc = b1[t];
        #pragma unroll
        for (int i = 0; i < 12; ++i) acc += qzs[i] * w1[t * 12 + i];
        hbuf[t] = fmaxf(acc, 0.0f);
    }
    __syncthreads();
    float acc = b2[t];
    #pragma unroll
    for (int k4 = 0; k4 < 16; ++k4) {
        const float4 wv = ((const float4*)w2)[t * 16 + k4];
        acc += wv.x * hbuf[k4 * 4 + 0] + wv.y * hbuf[k4 * 4 + 1]
             + wv.z * hbuf[k4 * 4 + 2] + wv.w * hbuf[k4 * 4 + 3];
    }
    out[b * 256 + t] = acc;
}

extern "C" void kernel_launch(void* const* d_in, const int* in_sizes, int n_in,
                              void* d_out, int out_size, void* d_ws, size_t ws_size,
                              hipStream_t stream) {
    const float* x  = (const float*)d_in[0];
    const float* rw = (const float*)d_in[1];
    const float* rb = (const float*)d_in[2];
    const float* w1 = (const float*)d_in[3];
    const float* b1 = (const float*)d_in[4];
    const float* w2 = (const float*)d_in[5];
    const float* b2 = (const float*)d_in[6];
    float* out = (float*)d_out;

    const int batch = in_sizes[0] / 48;   // x is [B,48]
    qreup_kernel<<<batch, 256, 0, stream>>>(x, rw, rb, w1, b1, w2, b2, out);
}

// Round 2
// 178.989 us; speedup vs baseline: 1.1166x; 1.1166x over previous
//
#include <hip/hip_runtime.h>
#include <math.h>

#define NLAYERS 3

// Inverse of the CNOT-ring permutation F (ring i -> (i+1)%12), GF(2)-linear.
__device__ __forceinline__ int finv(int c) {
    return ((c ^ (c << 1)) & 0xFFF) ^ ((c >> 11) * 3);
}
// LDS bank swizzle, GF(2)-linear: slot = i ^ ((i>>4)&15)
__device__ __forceinline__ int sig(int i) {
    return i ^ ((i >> 4) & 15);
}
// sig(finv(r)) for r in [0,16) — compile-time folds under unroll
__device__ __forceinline__ int gk(int r) {
    int j = (r ^ (r << 1)) & 0xFFF;
    return j ^ ((j >> 4) & 15);
}
// sig(finv(r<<8)) for r in [0,16) — compile-time folds under unroll
__device__ __forceinline__ int mk(int r) {
    int c = r << 8;
    int j = ((c ^ (c << 1)) & 0xFFF) ^ ((c >> 11) * 3);
    return j ^ ((j >> 4) & 15);
}

// Apply 4 single-qubit gates (wires wbase..wbase+3 = local bits 0..3) to a
// 16-amplitude register subcube. u row: {ct, 0, u01r, u01i, u10r, u10i, u11r, u11i}
__device__ __forceinline__ void apply4(float2 v[16], const float (*u)[8], int wbase) {
    #pragma unroll
    for (int b = 0; b < 4; ++b) {
        const float4 uA = *(const float4*)&u[wbase + b][0];
        const float4 uB = *(const float4*)&u[wbase + b][4];
        const float ct = uA.x, u01r = uA.z, u01i = uA.w;
        const float u10r = uB.x, u10i = uB.y, u11r = uB.z, u11i = uB.w;
        const int m = 1 << b;
        #pragma unroll
        for (int j = 0; j < 16; ++j) {
            if (j & m) continue;
            const float2 a0 = v[j], a1 = v[j | m];
            float2 n0, n1;
            n0.x = ct * a0.x + u01r * a1.x - u01i * a1.y;
            n0.y = ct * a0.y + u01r * a1.y + u01i * a1.x;
            n1.x = u10r * a0.x - u10i * a0.y + u11r * a1.x - u11i * a1.y;
            n1.y = u10r * a0.y + u10i * a0.x + u11r * a1.y + u11i * a1.x;
            v[j] = n0;
            v[j | m] = n1;
        }
    }
}

__global__ __launch_bounds__(256, 4)
void qreup_kernel(const float* __restrict__ x,
                  const float* __restrict__ rw,   // [12,3,4]
                  const float* __restrict__ rb,   // [12,3]
                  const float* __restrict__ w1,   // [64,12]
                  const float* __restrict__ b1,   // [64]
                  const float* __restrict__ w2,   // [256,64]
                  const float* __restrict__ b2,   // [256]
                  float* __restrict__ out)        // [B,256]
{
    __shared__ float2 st[4096];                   // 32 KB, swizzled layout sig(i)
    __shared__ __align__(16) float u[12][8];
    __shared__ float zred[4][12];
    __shared__ float qzs[12];
    __shared__ float hbuf[64];

    const int t = threadIdx.x;
    const int b = blockIdx.x;

    // ---- Phase A: params -> U3 matrices (threads 0..11)
    if (t < 12) {
        const int c = t;
        const float4 xv = ((const float4*)x)[b * 12 + c];
        float prm[3];
        #pragma unroll
        for (int p = 0; p < 3; ++p) {
            const float4 wv = ((const float4*)rw)[c * 3 + p];
            prm[p] = rb[c * 3 + p] + wv.x * xv.x + wv.y * xv.y + wv.z * xv.z + wv.w * xv.w;
        }
        float st_, ct_; sincosf(0.5f * prm[0], &st_, &ct_);
        float sp, cp;   sincosf(prm[1], &sp, &cp);
        float sl, cl;   sincosf(prm[2], &sl, &cl);
        const float cpl = cp * cl - sp * sl;
        const float spl = sp * cl + cp * sl;
        u[c][0] = ct_;        u[c][1] = 0.0f;
        u[c][2] = -cl * st_;  u[c][3] = -sl * st_;
        u[c][4] = cp * st_;   u[c][5] = sp * st_;
        u[c][6] = cpl * ct_;  u[c][7] = spl * ct_;
    }

    float2 v[16];

    // slot bases (all GF(2)-linear decompositions; fields verified disjoint)
    const int base0 = (t << 4) | (t & 15);         // G0 plain: slot = base0 ^ r
    const int base1 = ((t >> 4) << 8) | (t & 15);  // G1: slot = base1 ^ (17*r)
    const int base2 = t ^ (t >> 4);                // G2: slot = base2 ^ (r<<8)
    const int a_ = t << 4;                         // gather base: sig(finv(t<<4))
    const int gj = ((a_ ^ (a_ << 1)) & 0xFFF) ^ ((a_ >> 11) * 3);
    const int gbase = gj ^ ((gj >> 4) & 15);
    const int mbase = sig((t ^ (t << 1)) & 0xFFF); // sig(finv(t)), t<256

    // ================= layer 0 =================
    // G0: |0..0> directly in registers (no init pass needed — stores cover all slots)
    #pragma unroll
    for (int r = 0; r < 16; ++r) v[r] = make_float2(0.0f, 0.0f);
    if (t == 0) v[0].x = 1.0f;
    __syncthreads();                               // u[] ready
    apply4(v, u, 0);
    #pragma unroll
    for (int r = 0; r < 16; ++r) st[base0 ^ r] = v[r];
    __syncthreads();
    // G1 (wires 4-7): load/store same thread-private slots
    #pragma unroll
    for (int r = 0; r < 16; ++r) v[r] = st[base1 ^ (17 * r)];
    apply4(v, u, 4);
    #pragma unroll
    for (int r = 0; r < 16; ++r) st[base1 ^ (17 * r)] = v[r];
    __syncthreads();
    // G2 (wires 8-11)
    #pragma unroll
    for (int r = 0; r < 16; ++r) v[r] = st[base2 ^ (r << 8)];
    apply4(v, u, 8);
    #pragma unroll
    for (int r = 0; r < 16; ++r) st[base2 ^ (r << 8)] = v[r];
    __syncthreads();

    // ================= layers 1..2 =================
    for (int L = 1; L < NLAYERS; ++L) {
        // G0 with previous layer's CNOT ring folded into the gather
        #pragma unroll
        for (int r = 0; r < 16; ++r) v[r] = st[gbase ^ gk(r)];
        apply4(v, u, 0);
        __syncthreads();   // all gathers done before scattering to new slots
        #pragma unroll
        for (int r = 0; r < 16; ++r) st[base0 ^ r] = v[r];
        __syncthreads();
        #pragma unroll
        for (int r = 0; r < 16; ++r) v[r] = st[base1 ^ (17 * r)];
        apply4(v, u, 4);
        #pragma unroll
        for (int r = 0; r < 16; ++r) st[base1 ^ (17 * r)] = v[r];
        __syncthreads();
        #pragma unroll
        for (int r = 0; r < 16; ++r) v[r] = st[base2 ^ (r << 8)];
        apply4(v, u, 8);
        #pragma unroll
        for (int r = 0; r < 16; ++r) st[base2 ^ (r << 8)] = v[r];
        __syncthreads();
    }

    // ---- measurement (final CNOT ring folded into gather); c = (r<<8)|t
    float ztot = 0.f, z8 = 0.f, z9 = 0.f, z10 = 0.f, z11 = 0.f;
    #pragma unroll
    for (int r = 0; r < 16; ++r) {
        const float2 amp = st[mbase ^ mk(r)];
        const float pr = amp.x * amp.x + amp.y * amp.y;
        ztot += pr;
        z8  += (r & 1) ? -pr : pr;
        z9  += (r & 2) ? -pr : pr;
        z10 += (r & 4) ? -pr : pr;
        z11 += (r & 8) ? -pr : pr;
    }
    float zp[12];
    #pragma unroll
    for (int i = 0; i < 8; ++i)
        zp[i] = ((t >> i) & 1) ? -ztot : ztot;
    zp[8] = z8; zp[9] = z9; zp[10] = z10; zp[11] = z11;

    #pragma unroll
    for (int i = 0; i < 12; ++i) {
        float vv = zp[i];
        #pragma unroll
        for (int off = 32; off > 0; off >>= 1)
            vv += __shfl_xor(vv, off, 64);
        zp[i] = vv;
    }
    const int wave = t >> 6;
    if ((t & 63) == 0) {
        #pragma unroll
        for (int i = 0; i < 12; ++i) zred[wave][i] = zp[i];
    }
    __syncthreads();
    if (t < 12)
        qzs[t] = zred[0][t] + zred[1][t] + zred[2][t] + zred[3][t];
    __syncthreads();

    // ---- MLP head
    if (t < 64) {
        float acc = b1[t];
        #pragma unroll
        for (int i = 0; i < 12; ++i) acc += qzs[i] * w1[t * 12 + i];
        hbuf[t] = fmaxf(acc, 0.0f);
    }
    __syncthreads();
    float acc = b2[t];
    #pragma unroll
    for (int k4 = 0; k4 < 16; ++k4) {
        const float4 wv = ((const float4*)w2)[t * 16 + k4];
        acc += wv.x * hbuf[k4 * 4 + 0] + wv.y * hbuf[k4 * 4 + 1]
             + wv.z * hbuf[k4 * 4 + 2] + wv.w * hbuf[k4 * 4 + 3];
    }
    out[b * 256 + t] = acc;
}

extern "C" void kernel_launch(void* const* d_in, const int* in_sizes, int n_in,
                              void* d_out, int out_size, void* d_ws, size_t ws_size,
                              hipStream_t stream) {
    const float* x  = (const float*)d_in[0];
    const float* rw = (const float*)d_in[1];
    const float* rb = (const float*)d_in[2];
    const float* w1 = (const float*)d_in[3];
    const float* b1 = (const float*)d_in[4];
    const float* w2 = (const float*)d_in[5];
    const float* b2 = (const float*)d_in[6];
    float* out = (float*)d_out;

    const int batch = in_sizes[0] / 48;   // x is [B,48]
    qreup_kernel<<<batch, 256, 0, stream>>>(x, rw, rb, w1, b1, w2, b2, out);
}